// Round 5
// baseline (218.967 us; speedup 1.0000x reference)
//
#include <hip/hip_runtime.h>
#include <hip/hip_bf16.h>

#define LOG2E 1.4426950408889634f

typedef short bfrag8 __attribute__((ext_vector_type(8)));
typedef float accf4 __attribute__((ext_vector_type(4)));

__device__ __forceinline__ unsigned pack2(float a, float b) {
    __hip_bfloat162 h = __float22bfloat162_rn(make_float2(a, b));
    return *(unsigned*)&h;
}
__device__ __forceinline__ float bflo(unsigned u) { return __uint_as_float(u << 16); }
__device__ __forceinline__ float bfhi(unsigned u) { return __uint_as_float(u & 0xFFFF0000u); }

__device__ __forceinline__ void gload_lds16(const void* g, void* lds) {
    __builtin_amdgcn_global_load_lds(
        (const __attribute__((address_space(1))) unsigned int*)g,
        (__attribute__((address_space(3))) unsigned int*)lds, 16, 0, 0);
}

// ---------------------------------------------------------------------------
// Kernel 1: Wh = sent @ Ww^T + Wb ; outputs WhT bf16 [b][col][m], s1, s2
// (s1,s2 pre-scaled by LOG2E). Tile 128Mx256N, BK=64, 12 iters, 512 thr.
// T14 async-split staging: global f32 -> regs (issued BEFORE compute, counted
// vmcnt by compiler) -> cvt bf16 -> ds_write AFTER compute. No global_load_lds
// => barriers drain lgkm only, never vmcnt. All-bf16 LDS (96 KiB, XOR-swizzled).
// Ww read as f32 directly (L2-resident) — convW kernel eliminated.
// ---------------------------------------------------------------------------
__global__ __launch_bounds__(512) void gemm1_kernel(
    const float* __restrict__ sent, const float* __restrict__ Ww,
    const float* __restrict__ Wb, const float* __restrict__ aw,
    unsigned short* __restrict__ WhT, float* __restrict__ s1g,
    float* __restrict__ s2g)
{
    __shared__ char SMEM[98304];   // As bf16 [2][128][64] @0 (32K) | Bs bf16 [2][256][64] @32K (64K)
    const int brow = blockIdx.x;          // 0..255
    const int t = threadIdx.x;
    const int lane = t & 63, w = t >> 6;
    const int wr = w >> 2, wc = w & 3;
    const int l15 = lane & 15, l4 = lane >> 4;
    const float* abase = sent + (size_t)brow * 128 * 768;

    // staging mapping: A row 0..127 / chunk-pair; B col 0..255 / half
    const int ar = t >> 2, ac2 = (t & 3) << 1;   // A: 2 chunks (16B bf16 each) per thread
    const int bc = t >> 1, bh = t & 1;           // B: 4 chunks per thread

    accf4 acc[4][4];
#pragma unroll
    for (int i = 0; i < 4; ++i)
#pragma unroll
        for (int j = 0; j < 4; ++j)
            acc[i][j] = (accf4){0.f, 0.f, 0.f, 0.f};

    float4 aL[4], bL[8];
    auto LOADR = [&](int k0) {
        const float* ap = abase + ar * 768 + k0 + (ac2 << 3);
#pragma unroll
        for (int q = 0; q < 4; ++q) aL[q] = *(const float4*)(ap + (q << 2));
        const float* bp = Ww + bc * 768 + k0 + (bh << 5);
#pragma unroll
        for (int q = 0; q < 8; ++q) bL[q] = *(const float4*)(bp + (q << 2));
    };
    auto WRITE = [&](int buf) {
        char* Asb = SMEM + (buf << 14);
#pragma unroll
        for (int q = 0; q < 2; ++q) {
            uint4 pk;
            pk.x = pack2(aL[2 * q].x, aL[2 * q].y);
            pk.y = pack2(aL[2 * q].z, aL[2 * q].w);
            pk.z = pack2(aL[2 * q + 1].x, aL[2 * q + 1].y);
            pk.w = pack2(aL[2 * q + 1].z, aL[2 * q + 1].w);
            const int c = ac2 + q;
            *(uint4*)(Asb + (ar << 7) + ((c ^ (ar & 7)) << 4)) = pk;
        }
        char* Bsb = SMEM + 32768 + (buf << 15);
#pragma unroll
        for (int q = 0; q < 4; ++q) {
            uint4 pk;
            pk.x = pack2(bL[2 * q].x, bL[2 * q].y);
            pk.y = pack2(bL[2 * q].z, bL[2 * q].w);
            pk.z = pack2(bL[2 * q + 1].x, bL[2 * q + 1].y);
            pk.w = pack2(bL[2 * q + 1].z, bL[2 * q + 1].w);
            const int c = (bh << 2) + q;
            *(uint4*)(Bsb + (bc << 7) + ((c ^ (bc & 7)) << 4)) = pk;
        }
    };
    auto COMPUTE = [&](int buf) {
        const char* Ab = SMEM + (buf << 14);
        const char* Bb = SMEM + 32768 + (buf << 15);
#pragma unroll
        for (int kk = 0; kk < 2; ++kk) {
            const int s = (kk << 2) + l4;
            bfrag8 af[4], bf[4];
#pragma unroll
            for (int mi = 0; mi < 4; ++mi) {
                const int row = (wr << 6) + (mi << 4) + l15;
                af[mi] = *(const bfrag8*)(Ab + (row << 7) + ((s ^ (row & 7)) << 4));
            }
#pragma unroll
            for (int ni = 0; ni < 4; ++ni) {
                const int col = (wc << 6) + (ni << 4) + l15;
                bf[ni] = *(const bfrag8*)(Bb + (col << 7) + ((s ^ (col & 7)) << 4));
            }
#pragma unroll
            for (int mi = 0; mi < 4; ++mi)
#pragma unroll
                for (int ni = 0; ni < 4; ++ni)
                    acc[mi][ni] = __builtin_amdgcn_mfma_f32_16x16x32_bf16(
                        af[mi], bf[ni], acc[mi][ni], 0, 0, 0);
        }
    };

    LOADR(0);
    WRITE(0);
    __syncthreads();
    for (int it = 0; it < 12; ++it) {
        if (it < 11) LOADR((it + 1) << 6);    // issue loads early (latency hides under MFMA)
        COMPUTE(it & 1);
        if (it < 11) WRITE((it + 1) & 1);     // counted vmcnt here (compiler), disjoint buffer
        __syncthreads();                      // lgkm-only drain
    }

    // ---- epilogue: bias, transpose T[col][row] in LDS, s1/s2 ----
    unsigned short (*T)[136] = (unsigned short(*)[136])SMEM;   // 69,632 B < 98,304
    float (*sb1)[4] = (float(*)[4])(SMEM + 90112);
    float (*sb2)[4] = (float(*)[4])(SMEM + 92160);
    float sp1[16], sp2[16];
#pragma unroll
    for (int i = 0; i < 16; ++i) { sp1[i] = 0.f; sp2[i] = 0.f; }
#pragma unroll
    for (int ni = 0; ni < 4; ++ni) {
        const int colL = (wc << 6) + (ni << 4) + l15;
        const float wb  = Wb[colL];
        const float a1c = aw[colL] * LOG2E;
        const float a2c = aw[256 + colL] * LOG2E;
#pragma unroll
        for (int mi = 0; mi < 4; ++mi) {
            const int rowL = (wr << 6) + (mi << 4) + (l4 << 2);
            float v0 = acc[mi][ni][0] + wb, v1 = acc[mi][ni][1] + wb;
            float v2 = acc[mi][ni][2] + wb, v3 = acc[mi][ni][3] + wb;
            uint2 pk; pk.x = pack2(v0, v1); pk.y = pack2(v2, v3);
            *(uint2*)&T[colL][rowL] = pk;
            sp1[mi * 4 + 0] += v0 * a1c; sp1[mi * 4 + 1] += v1 * a1c;
            sp1[mi * 4 + 2] += v2 * a1c; sp1[mi * 4 + 3] += v3 * a1c;
            sp2[mi * 4 + 0] += v0 * a2c; sp2[mi * 4 + 1] += v1 * a2c;
            sp2[mi * 4 + 2] += v2 * a2c; sp2[mi * 4 + 3] += v3 * a2c;
        }
    }
#pragma unroll
    for (int d = 1; d < 16; d <<= 1)
#pragma unroll
        for (int i = 0; i < 16; ++i) {
            sp1[i] += __shfl_xor(sp1[i], d);
            sp2[i] += __shfl_xor(sp2[i], d);
        }
    if (l15 == 0)
#pragma unroll
        for (int mi = 0; mi < 4; ++mi)
#pragma unroll
            for (int reg = 0; reg < 4; ++reg) {
                const int rowL = (wr << 6) + (mi << 4) + (l4 << 2) + reg;
                sb1[rowL][wc] = sp1[mi * 4 + reg];
                sb2[rowL][wc] = sp2[mi * 4 + reg];
            }
    __syncthreads();
    {   // WhT write: thread -> (col, half-row-block), 128B contiguous m
        const int b = brow >> 3, m0 = (brow & 7) << 7;
        const int col = t >> 1, half = t & 1;
        unsigned short* dst = &WhT[(((size_t)b * 256 + col) << 10) + m0 + (half << 6)];
        const unsigned short* srcT = &T[col][half << 6];
#pragma unroll
        for (int q = 0; q < 8; ++q)
            *(uint4*)(dst + (q << 3)) = *(const uint4*)(srcT + (q << 3));
    }
    if (t < 128) {
        const int grow = brow * 128 + t;
        s1g[grow] = sb1[t][0] + sb1[t][1] + sb1[t][2] + sb1[t][3];
        s2g[grow] = sb2[t][0] + sb2[t][1] + sb2[t][2] + sb2[t][3];
    }
}

// ---------------------------------------------------------------------------
// Kernel 2: flash GEMM2 + elu + pooled partials. 128 rows x 256 cols/block,
// 8 blocks/batch (XCD-grouped), 512 thr. One barrier per m-step: Bs dbuf via
// gload_lds (src-swizzled) + Ps dbuf (compute P(t+1) while MFMA(t)).
// ---------------------------------------------------------------------------
__global__ __launch_bounds__(512) void flash_kernel(
    const unsigned short* __restrict__ WhT, const float* __restrict__ s1g,
    const float* __restrict__ s2g, float* __restrict__ ppart)
{
    __shared__ char SMEM[98304];   // Bs [2][256][64]bf16 @0 (64K) | Ps [2][128][64]bf16 @64K (32K)
    __shared__ float s2s[1024];
    __shared__ float zfull[128];
    __shared__ float wred[8];
    __shared__ float psum[2][256];
    const int bid0 = blockIdx.x;
    const int wg = ((bid0 & 7) << 5) + (bid0 >> 3);   // 256=8x32 bijective; batch's 8 blocks -> 1 XCD
    const int b = wg >> 3, nt = wg & 7, n0 = nt << 7;
    const int t = threadIdx.x;
    const int lane = t & 63, w = t >> 6;
    const int wr = w >> 2, wc = w & 3;
    const int l15 = lane & 15, l4 = lane >> 4;
    const int prow = t >> 2, pc0 = (t & 3) << 1;      // P-thread: row, chunk pair
    const unsigned short* wbase = WhT + ((size_t)b << 18);

    {   // s2s = s2 (log2-domain)
        const int i = t << 1;
        *(float2*)&s2s[i] = *(const float2*)&s2g[(b << 10) + i];
    }
    auto STAGEB = [&](int buf, int m0) {
#pragma unroll
        for (int q = 0; q < 4; ++q) {
            const int id = (q << 9) + t;
            const int col = id >> 3, c = id & 7;
            gload_lds16(wbase + ((size_t)col << 10) + m0 + ((c ^ (col & 7)) << 3),
                        SMEM + (buf << 15) + (id << 4));
        }
    };
    STAGEB(0, 0);
    const float s1r = s1g[(b << 10) + n0 + prow];
    __syncthreads();                                   // s2s visible + B0 drained
    float mm = fmaxf(s2s[t], s2s[t + 512]);
#pragma unroll
    for (int d = 1; d < 64; d <<= 1) mm = fmaxf(mm, __shfl_xor(mm, d));
    if (lane == 0) wred[w] = mm;
    __syncthreads();
    float s2mx = wred[0];
#pragma unroll
    for (int i = 1; i < 8; ++i) s2mx = fmaxf(s2mx, wred[i]);
    const float xm = s1r + s2mx;
    const float Mr = fmaxf(xm, 0.2f * xm);             // exact row max (lrelu monotone)

    accf4 acc[4][4];
#pragma unroll
    for (int i = 0; i < 4; ++i)
#pragma unroll
        for (int j = 0; j < 4; ++j)
            acc[i][j] = (accf4){0.f, 0.f, 0.f, 0.f};
    float zp = 0.f;

    auto PCOMP = [&](int buf, int mt) {
        const float* sp = &s2s[(mt << 6) + (pc0 << 3)];
        float4 x0 = *(const float4*)sp;
        float4 x1 = *(const float4*)(sp + 4);
        float4 x2 = *(const float4*)(sp + 8);
        float4 x3 = *(const float4*)(sp + 12);
        float xs[16] = {x0.x, x0.y, x0.z, x0.w, x1.x, x1.y, x1.z, x1.w,
                        x2.x, x2.y, x2.z, x2.w, x3.x, x3.y, x3.z, x3.w};
        unsigned u[8];
#pragma unroll
        for (int j = 0; j < 8; ++j) {
            float a = s1r + xs[2 * j], c = s1r + xs[2 * j + 1];
            a = fmaxf(a, 0.2f * a) - Mr;
            c = fmaxf(c, 0.2f * c) - Mr;
            u[j] = pack2(__builtin_amdgcn_exp2f(a), __builtin_amdgcn_exp2f(c));
            zp += bflo(u[j]) + bfhi(u[j]);             // Z of ROUNDED P
        }
        char* pb = SMEM + 65536 + (buf << 14) + (prow << 7);
        uint4 k0; k0.x = u[0]; k0.y = u[1]; k0.z = u[2]; k0.w = u[3];
        uint4 k1; k1.x = u[4]; k1.y = u[5]; k1.z = u[6]; k1.w = u[7];
        *(uint4*)(pb + ((pc0 ^ (prow & 7)) << 4)) = k0;
        *(uint4*)(pb + (((pc0 + 1) ^ (prow & 7)) << 4)) = k1;
    };
    auto MM = [&](int buf) {
        const char* Bb = SMEM + (buf << 15);
        const char* Pb = SMEM + 65536 + (buf << 14);
#pragma unroll
        for (int kk = 0; kk < 2; ++kk) {
            const int s = (kk << 2) + l4;
            bfrag8 af[4], bf[4];
#pragma unroll
            for (int mi = 0; mi < 4; ++mi) {
                const int row = (wr << 6) + (mi << 4) + l15;
                af[mi] = *(const bfrag8*)(Pb + (row << 7) + ((s ^ (row & 7)) << 4));
            }
#pragma unroll
            for (int ni = 0; ni < 4; ++ni) {
                const int col = (wc << 6) + (ni << 4) + l15;
                bf[ni] = *(const bfrag8*)(Bb + (col << 7) + ((s ^ (col & 7)) << 4));
            }
#pragma unroll
            for (int mi = 0; mi < 4; ++mi)
#pragma unroll
                for (int ni = 0; ni < 4; ++ni)
                    acc[mi][ni] = __builtin_amdgcn_mfma_f32_16x16x32_bf16(
                        af[mi], bf[ni], acc[mi][ni], 0, 0, 0);
        }
    };

    PCOMP(0, 0);
    __syncthreads();                                   // Ps[0] visible
    for (int mt = 0; mt < 16; ++mt) {
        if (mt < 15) {
            STAGEB((mt + 1) & 1, (mt + 1) << 6);       // async next B
            PCOMP((mt + 1) & 1, mt + 1);               // next P while MFMA below
        }
        MM(mt & 1);
        __syncthreads();                               // drain B(t+1), publish Ps(t+1)
    }

    // Z: 4 threads per row
    zp += __shfl_xor(zp, 1);
    zp += __shfl_xor(zp, 2);
    if ((lane & 3) == 0) zfull[prow] = zp;
    __syncthreads();

    // normalize, elu, column sums over 128 rows
    float rz[16];
#pragma unroll
    for (int mi = 0; mi < 4; ++mi)
#pragma unroll
        for (int r = 0; r < 4; ++r)
            rz[mi * 4 + r] = 1.0f / zfull[(wr << 6) + (mi << 4) + (l4 << 2) + r];
#pragma unroll
    for (int ni = 0; ni < 4; ++ni) {
        float cs = 0.f;
#pragma unroll
        for (int mi = 0; mi < 4; ++mi)
#pragma unroll
            for (int r = 0; r < 4; ++r) {
                float v = acc[mi][ni][r] * rz[mi * 4 + r];
                cs += v > 0.f ? v : (__expf(v) - 1.0f);
            }
        cs += __shfl_xor(cs, 16);
        cs += __shfl_xor(cs, 32);
        if (l4 == 0) psum[wr][(wc << 6) + (ni << 4) + l15] = cs;
    }
    __syncthreads();
    if (t < 256)
        ppart[(((size_t)b << 3) + nt) * 256 + t] = psum[0][t] + psum[1][t];
}

// ---------------------------------------------------------------------------
// Kernel 3: reduce 8 n-tile partials, mean-pool, tiny MLP. One block per b.
// ---------------------------------------------------------------------------
__global__ __launch_bounds__(256) void final_kernel(
    const float* __restrict__ ppart, const float* __restrict__ mlpw,
    const float* __restrict__ mlpb, float* __restrict__ out)
{
    __shared__ float r0[4], r1[4];
    const int b = blockIdx.x, t = threadIdx.x;
    float p = 0.f;
#pragma unroll
    for (int nt = 0; nt < 8; ++nt)
        p += ppart[(((size_t)b << 3) + nt) * 256 + t];
    float m0 = p * mlpw[t], m1 = p * mlpw[256 + t];
#pragma unroll
    for (int d = 1; d < 64; d <<= 1) {
        m0 += __shfl_xor(m0, d);
        m1 += __shfl_xor(m1, d);
    }
    if ((t & 63) == 0) { r0[t >> 6] = m0; r1[t >> 6] = m1; }
    __syncthreads();
    if (t == 0) out[b * 2 + 0] = (r0[0] + r0[1] + r0[2] + r0[3]) * (1.f / 1024.f) + mlpb[0];
    if (t == 1) out[b * 2 + 1] = (r1[0] + r1[1] + r1[2] + r1[3]) * (1.f / 1024.f) + mlpb[1];
}

extern "C" void kernel_launch(void* const* d_in, const int* in_sizes, int n_in,
                              void* d_out, int out_size, void* d_ws, size_t ws_size,
                              hipStream_t stream) {
    const float* sent = (const float*)d_in[0];
    // d_in[1] = batch_e: provably unused (event_mask = where(cond,0.9,0.1) > 0 always)
    const float* Ww   = (const float*)d_in[2];
    const float* Wb   = (const float*)d_in[3];
    const float* aw   = (const float*)d_in[4];
    const float* mlpw = (const float*)d_in[5];
    const float* mlpb = (const float*)d_in[6];
    float* out = (float*)d_out;

    char* ws = (char*)d_ws;
    unsigned short* WhT  = (unsigned short*)ws;              // 16,777,216 B
    float*          s1g  = (float*)(ws + 16777216);          //    131,072 B
    float*          s2g  = s1g + 32768;                      //    131,072 B
    float*          ppart= s2g + 32768;                      //    262,144 B (32*8*256)

    gemm1_kernel<<<256, 512, 0, stream>>>(sent, Ww, Wb, aw, WhT, s1g, s2g);
    flash_kernel<<<256, 512, 0, stream>>>(WhT, s1g, s2g, ppart);
    final_kernel<<<32, 256, 0, stream>>>(ppart, mlpw, mlpb, out);
}